// Round 1
// baseline (5097.339 us; speedup 1.0000x reference)
//
#include <hip/hip_runtime.h>
#include <hip/hip_bf16.h>

typedef __hip_bfloat16 bf16;

// Problem constants (B=1)
#define HH 256     // n_seqs
#define WW 256     // length
#define DD 64      // dim
#define PP 128     // pair dim
#define NHEADS 8
#define DHEAD 64
#define INNER 512  // NHEADS*DHEAD
#define NROWS 65536  // HH*WW

// ws layout (bytes):
//   q  : NROWS*512 bf16 = 67,108,864
//   k  : NROWS*512 bf16 = 67,108,864
//   v  : NROWS*512 bf16 = 67,108,864
//   dots: 8*256*256 f32 =  2,097,152
// total = 203,423,744 bytes (~194 MiB). Region q/k/v reused by width then height.

__device__ __forceinline__ void unpack8(const uint4 r, float* f) {
  const unsigned int* u = reinterpret_cast<const unsigned int*>(&r);
#pragma unroll
  for (int i = 0; i < 4; i++) {
    f[2 * i + 0] = __uint_as_float(u[i] << 16);
    f[2 * i + 1] = __uint_as_float(u[i] & 0xffff0000u);
  }
}

// ---------------------------------------------------------------- init output
__global__ void __launch_bounds__(256) k_init_out(const float* __restrict__ bw,
                                                  const float* __restrict__ bh,
                                                  float* __restrict__ out) {
  int idx = blockIdx.x * 256 + threadIdx.x;  // < NROWS*64
  out[idx] = 0.5f * (bw[idx & 63] + bh[idx & 63]);
}

// ---------------------------------------------------------------- QKV: x @ [Wq | Wkv] -> q,k,v (bf16)
// grid (NROWS/16, 6), block 256. Tile: 16 rows x 256 cols.
__global__ void __launch_bounds__(256) k_qkv(const float* __restrict__ x,
                                             const float* __restrict__ Wq,    // 64x512
                                             const float* __restrict__ Wkv,   // 64x1024
                                             bf16* __restrict__ q, bf16* __restrict__ kk,
                                             bf16* __restrict__ v) {
  __shared__ __align__(16) float xs[16][64];
  const int r0 = blockIdx.x * 16;
  const int tid = threadIdx.x;
  // load 16x64 f32 x-tile (contiguous) with float4
  ((float4*)xs)[tid] = ((const float4*)(x + (size_t)r0 * 64))[tid];
  __syncthreads();

  const int c = blockIdx.y * 256 + tid;  // 0..1535
  const float* Wcol;
  int ldw;
  if (c < 512) { Wcol = Wq + c; ldw = 512; }
  else         { Wcol = Wkv + (c - 512); ldw = 1024; }

  float acc[16];
#pragma unroll
  for (int r = 0; r < 16; r++) acc[r] = 0.f;

  for (int k0 = 0; k0 < 64; k0 += 4) {
    const float w0 = Wcol[(k0 + 0) * ldw];
    const float w1 = Wcol[(k0 + 1) * ldw];
    const float w2 = Wcol[(k0 + 2) * ldw];
    const float w3 = Wcol[(k0 + 3) * ldw];
#pragma unroll
    for (int r = 0; r < 16; r++) {
      const float4 xv = *(const float4*)&xs[r][k0];
      acc[r] += xv.x * w0 + xv.y * w1 + xv.z * w2 + xv.w * w3;
    }
  }

  bf16* dst;
  int cc;
  if (c < 512)       { dst = q;  cc = c; }
  else if (c < 1024) { dst = kk; cc = c - 512; }
  else               { dst = v;  cc = c - 1024; }
#pragma unroll
  for (int r = 0; r < 16; r++)
    dst[(size_t)(r0 + r) * 512 + cc] = __float2bfloat16(acc[r]);
}

// ---------------------------------------------------------------- width attention + fused out-proj
// grid (WW, NHEADS), block 256 (thread = position h). atomicAdd 0.5*(ow_head @ Wout_slice) into out.
__global__ void __launch_bounds__(256) k_width_attn(const bf16* __restrict__ q,
                                                    const bf16* __restrict__ kk,
                                                    const bf16* __restrict__ v,
                                                    const float* __restrict__ Wout,  // 512x64
                                                    float* __restrict__ out) {
  __shared__ __align__(16) bf16 ks[256 * 64];  // 32 KB
  __shared__ __align__(16) bf16 vs[256 * 64];  // 32 KB
  const int w = blockIdx.x, head = blockIdx.y, tid = threadIdx.x;

  // cooperative load of K,V column slabs (h=0..255, d=0..63) for (w, head)
#pragma unroll
  for (int it = 0; it < 8; it++) {
    const int idx = it * 256 + tid;  // uint4 units (8 bf16), 2048 total
    const int h = idx >> 3, ch = idx & 7;
    const size_t base = ((size_t)(h * 256 + w) * 512 + head * 64);
    ((uint4*)ks)[idx] = *(const uint4*)(kk + base + ch * 8);
    ((uint4*)vs)[idx] = *(const uint4*)(v + base + ch * 8);
  }

  // this thread's q row (h = tid)
  float qr[64];
  {
    const uint4* qsrc = (const uint4*)(q + ((size_t)(tid * 256 + w) * 512 + head * 64));
#pragma unroll
    for (int c8 = 0; c8 < 8; c8++) unpack8(qsrc[c8], &qr[c8 * 8]);
  }
  __syncthreads();

  float o[64];
#pragma unroll
  for (int d = 0; d < 64; d++) o[d] = 0.f;
  float l = 0.f;

  for (int j = 0; j < 256; j++) {
    const uint4* krow = (const uint4*)ks + j * 8;
    float s = 0.f;
#pragma unroll
    for (int c8 = 0; c8 < 8; c8++) {
      float f[8];
      unpack8(krow[c8], f);
#pragma unroll
      for (int t = 0; t < 8; t++) s += qr[c8 * 8 + t] * f[t];
    }
    const float p = __expf(s * 0.125f);  // logits are small; no max-sub needed
    l += p;
    const uint4* vrow = (const uint4*)vs + j * 8;
#pragma unroll
    for (int c8 = 0; c8 < 8; c8++) {
      float f[8];
      unpack8(vrow[c8], f);
#pragma unroll
      for (int t = 0; t < 8; t++) o[c8 * 8 + t] += p * f[t];
    }
  }
  const float inv = 1.f / l;
#pragma unroll
  for (int d = 0; d < 64; d++) o[d] *= inv;

  __syncthreads();
  // reuse ks region for Wout slice [64][64] f32 (16 KB)
  float* wlds = (float*)ks;
  for (int idx = tid; idx < 4096; idx += 256)
    wlds[idx] = Wout[(head * 64 + (idx >> 6)) * 64 + (idx & 63)];
  __syncthreads();

  const size_t obase = ((size_t)(tid * 256 + w)) * 64;  // out[h=tid, w, :]
  for (int c = 0; c < 64; c++) {
    float s = 0.f;
#pragma unroll
    for (int d = 0; d < 64; d++) s += o[d] * wlds[d * 64 + c];
    atomicAdd(&out[obase + c], 0.5f * s);
  }
}

// ---------------------------------------------------------------- height tied dots: K=16384 GEMM
// grid (16 tiles of 64x64, 8 heads, 4 r-chunks), block 256 = 16x16 threads, 4x4 per thread.
__global__ void __launch_bounds__(256) k_dots(const bf16* __restrict__ q,
                                              const bf16* __restrict__ kk,
                                              float* __restrict__ dots) {
  __shared__ __align__(16) float qs[64][68];   // pad 68 -> conflict-free
  __shared__ __align__(16) float ks2[64][68];
  const int tile = blockIdx.x, head = blockIdx.y, rc = blockIdx.z;
  const int i0 = (tile >> 2) * 64, j0 = (tile & 3) * 64;
  const int tx = threadIdx.x & 15, ty = threadIdx.x >> 4;

  float acc[4][4];
#pragma unroll
  for (int a = 0; a < 4; a++)
#pragma unroll
    for (int b = 0; b < 4; b++) acc[a][b] = 0.f;

  for (int rr = 0; rr < 64; rr++) {
    const int r = rc * 64 + rr;
    __syncthreads();
    {  // load 64x64 q-tile and k-tile (bf16 -> f32 LDS)
      const int row = threadIdx.x >> 2, ch = (threadIdx.x & 3) * 16;
      const bf16* qsrc = q + ((size_t)(r * 256 + i0 + row) * 512 + head * 64 + ch);
      const bf16* ksrc = kk + ((size_t)(r * 256 + j0 + row) * 512 + head * 64 + ch);
      uint4 ra = *(const uint4*)qsrc, rb = *(const uint4*)(qsrc + 8);
      float f[16];
      unpack8(ra, f); unpack8(rb, f + 8);
#pragma unroll
      for (int t = 0; t < 16; t += 4) *(float4*)&qs[row][ch + t] = *(float4*)&f[t];
      ra = *(const uint4*)ksrc; rb = *(const uint4*)(ksrc + 8);
      unpack8(ra, f); unpack8(rb, f + 8);
#pragma unroll
      for (int t = 0; t < 16; t += 4) *(float4*)&ks2[row][ch + t] = *(float4*)&f[t];
    }
    __syncthreads();

#pragma unroll
    for (int d = 0; d < 64; d += 4) {
      float4 qa[4], kb[4];
#pragma unroll
      for (int a = 0; a < 4; a++) qa[a] = *(const float4*)&qs[ty + 16 * a][d];
#pragma unroll
      for (int b = 0; b < 4; b++) kb[b] = *(const float4*)&ks2[tx + 16 * b][d];
#pragma unroll
      for (int a = 0; a < 4; a++)
#pragma unroll
        for (int b = 0; b < 4; b++)
          acc[a][b] += qa[a].x * kb[b].x + qa[a].y * kb[b].y + qa[a].z * kb[b].z + qa[a].w * kb[b].w;
    }
  }

  const float sc = 1.f / 128.f;  // dh^-0.5 * H^-0.5
#pragma unroll
  for (int a = 0; a < 4; a++)
#pragma unroll
    for (int b = 0; b < 4; b++)
      atomicAdd(&dots[(size_t)head * 65536 + (i0 + ty + 16 * a) * 256 + (j0 + tx + 16 * b)],
                acc[a][b] * sc);
}

// ---------------------------------------------------------------- pair bias: LN + @W_pair, add to dots
// grid 65536 (= i*256+j), block 128 (thread = p)
__global__ void __launch_bounds__(128) k_pb_add(const float* __restrict__ pb,
                                                const float* __restrict__ g,
                                                const float* __restrict__ bb,
                                                const float* __restrict__ Wp,  // 128x8
                                                float* __restrict__ dots) {
  __shared__ float sn[128];
  __shared__ float red[2];
  const int ij = blockIdx.x, t = threadIdx.x;
  const float xv = pb[(size_t)ij * 128 + t];

  float s = xv;
#pragma unroll
  for (int o = 1; o < 64; o <<= 1) s += __shfl_xor(s, o, 64);
  if ((t & 63) == 0) red[t >> 6] = s;
  __syncthreads();
  const float mu = (red[0] + red[1]) * (1.f / 128.f);
  __syncthreads();

  const float dx = xv - mu;
  float s2 = dx * dx;
#pragma unroll
  for (int o = 1; o < 64; o <<= 1) s2 += __shfl_xor(s2, o, 64);
  if ((t & 63) == 0) red[t >> 6] = s2;
  __syncthreads();
  const float var = (red[0] + red[1]) * (1.f / 128.f);

  sn[t] = dx * rsqrtf(var + 1e-5f) * g[t] + bb[t];
  __syncthreads();

  if (t < 8) {
    float acc = 0.f;
#pragma unroll 16
    for (int p = 0; p < 128; p++) acc += sn[p] * Wp[p * 8 + t];
    dots[(size_t)t * 65536 + ij] += acc;  // unique (ij) per block -> plain RMW ok
  }
}

// ---------------------------------------------------------------- softmax over j (in-place on dots)
// grid (256 rows, 8 heads), block 256
__global__ void __launch_bounds__(256) k_softmax(float* __restrict__ dots) {
  __shared__ float red[4];
  const int i = blockIdx.x, head = blockIdx.y, t = threadIdx.x;
  const size_t base = (size_t)head * 65536 + i * 256;
  const float e = __expf(dots[base + t]);  // logits bounded (~|5|), safe
  float s = e;
#pragma unroll
  for (int o = 1; o < 64; o <<= 1) s += __shfl_xor(s, o, 64);
  if ((t & 63) == 0) red[t >> 6] = s;
  __syncthreads();
  const float S = red[0] + red[1] + red[2] + red[3];
  dots[base + t] = e / S;
}

// ---------------------------------------------------------------- height PV + fused out-proj
// grid (HH=256 r, 8 heads), block 256 (thread = position i along W)
__global__ void __launch_bounds__(256) k_h_attnv(const float* __restrict__ attn,
                                                 const bf16* __restrict__ v,
                                                 const float* __restrict__ Wout,  // 512x64
                                                 float* __restrict__ out) {
  __shared__ __align__(16) bf16 vs[256 * 64];  // 32 KB
  const int r = blockIdx.x, head = blockIdx.y, tid = threadIdx.x;

#pragma unroll
  for (int it = 0; it < 8; it++) {
    const int idx = it * 256 + tid;  // uint4 units
    const int j = idx >> 3, ch = idx & 7;
    ((uint4*)vs)[idx] = *(const uint4*)(v + ((size_t)(r * 256 + j) * 512 + head * 64 + ch * 8));
  }
  __syncthreads();

  const float* arow = attn + (size_t)head * 65536 + tid * 256;
  float o[64];
#pragma unroll
  for (int d = 0; d < 64; d++) o[d] = 0.f;

  for (int j = 0; j < 256; j++) {
    const float p = arow[j];
    const uint4* vrow = (const uint4*)vs + j * 8;
#pragma unroll
    for (int c8 = 0; c8 < 8; c8++) {
      float f[8];
      unpack8(vrow[c8], f);
#pragma unroll
      for (int t = 0; t < 8; t++) o[c8 * 8 + t] += p * f[t];
    }
  }

  __syncthreads();
  float* wlds = (float*)vs;  // reuse for Wout_h slice
  for (int idx = tid; idx < 4096; idx += 256)
    wlds[idx] = Wout[(head * 64 + (idx >> 6)) * 64 + (idx & 63)];
  __syncthreads();

  const size_t obase = ((size_t)(r * 256 + tid)) * 64;  // out[h=r, w=tid, :]
  for (int c = 0; c < 64; c++) {
    float s = 0.f;
#pragma unroll
    for (int d = 0; d < 64; d++) s += o[d] * wlds[d * 64 + c];
    atomicAdd(&out[obase + c], 0.5f * s);
  }
}

// ================================================================ launch
extern "C" void kernel_launch(void* const* d_in, const int* in_sizes, int n_in,
                              void* d_out, int out_size, void* d_ws, size_t ws_size,
                              hipStream_t stream) {
  const float* x       = (const float*)d_in[0];
  const float* pair    = (const float*)d_in[1];
  const float* Wq_w    = (const float*)d_in[2];
  const float* Wkv_w   = (const float*)d_in[3];
  const float* Wout_w  = (const float*)d_in[4];
  const float* bout_w  = (const float*)d_in[5];
  const float* Wq_h    = (const float*)d_in[6];
  const float* Wkv_h   = (const float*)d_in[7];
  const float* Wout_h  = (const float*)d_in[8];
  const float* bout_h  = (const float*)d_in[9];
  const float* ln_g    = (const float*)d_in[10];
  const float* ln_b    = (const float*)d_in[11];
  const float* W_pair  = (const float*)d_in[12];
  float* out = (float*)d_out;

  const size_t NE = (size_t)NROWS * 512;  // 33,554,432 elements
  bf16* q = (bf16*)d_ws;
  bf16* k = q + NE;
  bf16* v = k + NE;
  float* dots = (float*)(v + NE);  // 8*65536 f32

  // out = 0.5*(bout_w + bout_h) broadcast
  k_init_out<<<NROWS * 64 / 256, 256, 0, stream>>>(bout_w, bout_h, out);

  // -------- width attention --------
  k_qkv<<<dim3(NROWS / 16, 6), 256, 0, stream>>>(x, Wq_w, Wkv_w, q, k, v);
  k_width_attn<<<dim3(WW, NHEADS), 256, 0, stream>>>(q, k, v, Wout_w, out);

  // -------- height attention (reuses q/k/v region) --------
  k_qkv<<<dim3(NROWS / 16, 6), 256, 0, stream>>>(x, Wq_h, Wkv_h, q, k, v);
  hipMemsetAsync(dots, 0, (size_t)8 * 65536 * sizeof(float), stream);
  k_dots<<<dim3(16, NHEADS, 4), 256, 0, stream>>>(q, k, dots);
  k_pb_add<<<65536, 128, 0, stream>>>(pair, ln_g, ln_b, W_pair, dots);
  k_softmax<<<dim3(256, NHEADS), 256, 0, stream>>>(dots);
  k_h_attnv<<<dim3(HH, NHEADS), 256, 0, stream>>>(dots, v, Wout_h, out);
}

// Round 2
// 1006.216 us; speedup vs baseline: 5.0658x; 5.0658x over previous
//
#include <hip/hip_runtime.h>
#include <hip/hip_bf16.h>

typedef __hip_bfloat16 bf16;
typedef __attribute__((ext_vector_type(8))) short bf16x8;
typedef __attribute__((ext_vector_type(4))) float f32x4;

#define MFMA16(a, b, c) __builtin_amdgcn_mfma_f32_16x16x32_bf16(a, b, c, 0, 0, 0)

// Problem constants (B=1)
#define HH 256
#define WW 256
#define DD 64
#define PP 128
#define NHEADS 8
#define DHEAD 64
#define NROWS 65536

// ws layout: q | k | v (bf16, 67MB each) | dots (f32 2MB)  = 203.4 MB (same as proven r1)
// P_bf16 (1 MB) aliases q (q is dead once k_dots finishes).

// MFMA fragment conventions (verified m89/m91/m120):
//   A-frag: lane l holds A[m = l&15][k = (l>>4)*8 + t], t=0..7  (contiguous k)
//   B-frag: lane l holds B[n = l&15][k = (l>>4)*8 + t]          (contiguous k)
//   C/D   : lane l, reg r -> (col = l&15, row = (l>>4)*4 + r)
//   D[m][n] = sum_k A[m][k]*B[n][k]   (i.e. A @ B^T in frag terms)

// ---------------------------------------------------------------- init output
__global__ void __launch_bounds__(256) k_init_out(const float* __restrict__ bw,
                                                  const float* __restrict__ bh,
                                                  float* __restrict__ out) {
  int idx = blockIdx.x * 256 + threadIdx.x;
  out[idx] = 0.5f * (bw[idx & 63] + bh[idx & 63]);
}

// ---------------------------------------------------------------- QKV (f32 vector, kept from r1)
__global__ void __launch_bounds__(256) k_qkv(const float* __restrict__ x,
                                             const float* __restrict__ Wq,
                                             const float* __restrict__ Wkv,
                                             bf16* __restrict__ q, bf16* __restrict__ kk,
                                             bf16* __restrict__ v) {
  __shared__ __align__(16) float xs[16][64];
  const int r0 = blockIdx.x * 16;
  const int tid = threadIdx.x;
  ((float4*)xs)[tid] = ((const float4*)(x + (size_t)r0 * 64))[tid];
  __syncthreads();

  const int c = blockIdx.y * 256 + tid;
  const float* Wcol;
  int ldw;
  if (c < 512) { Wcol = Wq + c; ldw = 512; }
  else         { Wcol = Wkv + (c - 512); ldw = 1024; }

  float acc[16];
#pragma unroll
  for (int r = 0; r < 16; r++) acc[r] = 0.f;

  for (int k0 = 0; k0 < 64; k0 += 4) {
    const float w0 = Wcol[(k0 + 0) * ldw];
    const float w1 = Wcol[(k0 + 1) * ldw];
    const float w2 = Wcol[(k0 + 2) * ldw];
    const float w3 = Wcol[(k0 + 3) * ldw];
#pragma unroll
    for (int r = 0; r < 16; r++) {
      const float4 xv = *(const float4*)&xs[r][k0];
      acc[r] += xv.x * w0 + xv.y * w1 + xv.z * w2 + xv.w * w3;
    }
  }

  bf16* dst;
  int cc;
  if (c < 512)       { dst = q;  cc = c; }
  else if (c < 1024) { dst = kk; cc = c - 512; }
  else               { dst = v;  cc = c - 1024; }
#pragma unroll
  for (int r = 0; r < 16; r++)
    dst[(size_t)(r0 + r) * 512 + cc] = __float2bfloat16(acc[r]);
}

// ---------------------------------------------------------------- width attention (MFMA) + fused proj
// grid (WW, NHEADS), block 256 = 4 waves; wave handles 64-row Q strip.
// LDS: Vt[64][264] @0 (33792) | Ps[wave][64][40] @33792 (4x5120) | Wtr[64][72] @54272 (9216)
//      Ot[wave][64][72] @0 (4x9216=36864) reuses Vt+Ps after barrier. Total 63488.
__global__ void __launch_bounds__(256, 2)
k_width_attn(const bf16* __restrict__ q, const bf16* __restrict__ kk,
             const bf16* __restrict__ v, const float* __restrict__ Wout,
             float* __restrict__ out) {
  __shared__ __align__(16) char smem[63488];
  bf16* Vt  = (bf16*)smem;
  bf16* Wtr = (bf16*)(smem + 54272);
  const int w = blockIdx.x, head = blockIdx.y;
  const int tid = threadIdx.x, lane = tid & 63, wv = tid >> 6;
  bf16* Ps = (bf16*)(smem + 33792 + wv * 5120);
  bf16* Ot = (bf16*)(smem + (size_t)wv * 9216);
  const int m16 = lane & 15, kq = lane >> 4;

  // stage Vt[d][j] = V[j][d] (thread t = row j, 128B contiguous read, 2-lane/bank writes)
  {
    const bf16* src = v + ((size_t)(tid * 256 + w) * 512 + head * 64);
    uint4 rr[8];
#pragma unroll
    for (int c = 0; c < 8; c++) rr[c] = ((const uint4*)src)[c];
#pragma unroll
    for (int c = 0; c < 8; c++) {
      const bf16* e = (const bf16*)&rr[c];
#pragma unroll
      for (int t = 0; t < 8; t++) Vt[(c * 8 + t) * 264 + tid] = e[t];
    }
  }
  // stage Wtr[c][d] = Wout[head*64+d][c]
#pragma unroll
  for (int s = 0; s < 16; s++) {
    int idx = s * 256 + tid;
    int d = idx >> 6, c = idx & 63;
    Wtr[c * 72 + d] = __float2bfloat16(Wout[(head * 64 + d) * 64 + c]);
  }
  // preload Q A-frags (global, scattered 16B but 100% line use via L2)
  bf16x8 qf[4][2];
  const int i0 = wv * 64;
#pragma unroll
  for (int it = 0; it < 4; it++) {
    const bf16* b = q + ((size_t)((i0 + it * 16 + m16) * 256 + w) * 512 + head * 64 + kq * 8);
    qf[it][0] = *(const bf16x8*)b;
    qf[it][1] = *(const bf16x8*)(b + 32);
  }
  __syncthreads();

  f32x4 acc[4][4];
#pragma unroll
  for (int a = 0; a < 4; a++)
#pragma unroll
    for (int b = 0; b < 4; b++) acc[a][b] = (f32x4){0.f, 0.f, 0.f, 0.f};
  float rsum[4][4];
#pragma unroll
  for (int a = 0; a < 4; a++)
#pragma unroll
    for (int r = 0; r < 4; r++) rsum[a][r] = 0.f;

  auto loadK = [&](int jc, bf16x8 kf[2][2]) {
#pragma unroll
    for (int jt = 0; jt < 2; jt++) {
      const bf16* b = kk + ((size_t)((jc * 32 + jt * 16 + m16) * 256 + w) * 512 + head * 64 + kq * 8);
      kf[jt][0] = *(const bf16x8*)b;
      kf[jt][1] = *(const bf16x8*)(b + 32);
    }
  };
  bf16x8 kcur[2][2];
  loadK(0, kcur);

#pragma unroll 1
  for (int jc = 0; jc < 8; jc++) {  // j-chunk of 32
    bf16x8 knext[2][2];
    if (jc < 7) loadK(jc + 1, knext);  // prefetch hides VMEM latency
    // S = Q K^T -> exp -> Ps (per-wave private, no barrier)
#pragma unroll
    for (int it = 0; it < 4; it++)
#pragma unroll
      for (int jt = 0; jt < 2; jt++) {
        f32x4 s = (f32x4){0.f, 0.f, 0.f, 0.f};
        s = MFMA16(qf[it][0], kcur[jt][0], s);
        s = MFMA16(qf[it][1], kcur[jt][1], s);
#pragma unroll
        for (int r = 0; r < 4; r++) {
          float p = __expf(s[r] * 0.125f);  // dh^-0.5; logits bounded, no max-sub
          rsum[it][r] += p;
          Ps[(it * 16 + kq * 4 + r) * 40 + jt * 16 + m16] = __float2bfloat16(p);
        }
      }
    // PV: A from Ps (k=j within chunk), B from Vt
    bf16x8 pf[4], vf[4];
#pragma unroll
    for (int it = 0; it < 4; it++)
      pf[it] = *(const bf16x8*)&Ps[(it * 16 + m16) * 40 + kq * 8];
#pragma unroll
    for (int dt = 0; dt < 4; dt++)
      vf[dt] = *(const bf16x8*)&Vt[(dt * 16 + m16) * 264 + jc * 32 + kq * 8];
#pragma unroll
    for (int it = 0; it < 4; it++)
#pragma unroll
      for (int dt = 0; dt < 4; dt++) acc[it][dt] = MFMA16(pf[it], vf[dt], acc[it][dt]);
    if (jc < 7) {
#pragma unroll
      for (int jt = 0; jt < 2; jt++) {
        kcur[jt][0] = knext[jt][0];
        kcur[jt][1] = knext[jt][1];
      }
    }
  }

  // full row sums: reduce over 16 col-lanes (xor 1,2,4,8 stays in group)
#pragma unroll
  for (int it = 0; it < 4; it++)
#pragma unroll
    for (int r = 0; r < 4; r++) {
      float s = rsum[it][r];
      s += __shfl_xor(s, 1); s += __shfl_xor(s, 2);
      s += __shfl_xor(s, 4); s += __shfl_xor(s, 8);
      rsum[it][r] = 1.f / s;
    }
  __syncthreads();  // Vt/Ps dead -> reuse as Ot
  // normalized O -> Ot (row-major bf16, per-wave region)
#pragma unroll
  for (int it = 0; it < 4; it++)
#pragma unroll
    for (int dt = 0; dt < 4; dt++)
#pragma unroll
      for (int r = 0; r < 4; r++)
        Ot[(it * 16 + kq * 4 + r) * 72 + dt * 16 + m16] =
            __float2bfloat16(acc[it][dt][r] * rsum[it][r]);
  // proj: C2[i][c] = sum_d O[i][d] * Wtr[c][d]
  bf16x8 of[4][2], wf[4][2];
#pragma unroll
  for (int it = 0; it < 4; it++) {
    of[it][0] = *(const bf16x8*)&Ot[(it * 16 + m16) * 72 + kq * 8];
    of[it][1] = *(const bf16x8*)&Ot[(it * 16 + m16) * 72 + 32 + kq * 8];
  }
#pragma unroll
  for (int ct = 0; ct < 4; ct++) {
    wf[ct][0] = *(const bf16x8*)&Wtr[(ct * 16 + m16) * 72 + kq * 8];
    wf[ct][1] = *(const bf16x8*)&Wtr[(ct * 16 + m16) * 72 + 32 + kq * 8];
  }
#pragma unroll
  for (int it = 0; it < 4; it++)
#pragma unroll
    for (int ct = 0; ct < 4; ct++) {
      f32x4 c2 = (f32x4){0.f, 0.f, 0.f, 0.f};
      c2 = MFMA16(of[it][0], wf[ct][0], c2);
      c2 = MFMA16(of[it][1], wf[ct][1], c2);
#pragma unroll
      for (int r = 0; r < 4; r++) {
        int i = i0 + it * 16 + kq * 4 + r;  // = h
        atomicAdd(&out[(size_t)(i * 256 + w) * 64 + ct * 16 + m16], 0.5f * c2[r]);
      }
    }
}

// ---------------------------------------------------------------- height tied dots (MFMA)
// grid (4 tiles of 128x128, 8 heads, 16 r-chunks of 16), block 256 = 4 waves (i-strip 32 each)
// LDS: Qs[128][72] | Ks[128][72] = 36864
__global__ void __launch_bounds__(256, 2)
k_dots(const bf16* __restrict__ q, const bf16* __restrict__ kk, float* __restrict__ dots) {
  __shared__ __align__(16) char smem[36864];
  bf16* Qs = (bf16*)smem;
  bf16* Ks = (bf16*)(smem + 18432);
  const int tile = blockIdx.x, head = blockIdx.y, rc = blockIdx.z;
  const int i0 = (tile >> 1) * 128, j0 = (tile & 1) * 128;
  const int tid = threadIdx.x, lane = tid & 63, wv = tid >> 6;
  const int m16 = lane & 15, kq = lane >> 4;
  const int ioff = wv * 32;

  f32x4 acc[2][8];
#pragma unroll
  for (int a = 0; a < 2; a++)
#pragma unroll
    for (int b = 0; b < 8; b++) acc[a][b] = (f32x4){0.f, 0.f, 0.f, 0.f};

#pragma unroll 1
  for (int rr = 0; rr < 16; rr++) {
    const int rrow = rc * 16 + rr;
    __syncthreads();
#pragma unroll
    for (int s = 0; s < 4; s++) {
      int idx = s * 256 + tid;
      int row = idx >> 3, ch = idx & 7;
      *(uint4*)&Qs[row * 72 + ch * 8] =
          *(const uint4*)(q + ((size_t)(rrow * 256 + i0 + row) * 512 + head * 64 + ch * 8));
      *(uint4*)&Ks[row * 72 + ch * 8] =
          *(const uint4*)(kk + ((size_t)(rrow * 256 + j0 + row) * 512 + head * 64 + ch * 8));
    }
    __syncthreads();
#pragma unroll
    for (int ks = 0; ks < 2; ks++) {
      bf16x8 af[2], bfr[8];
#pragma unroll
      for (int it = 0; it < 2; it++)
        af[it] = *(const bf16x8*)&Qs[(ioff + it * 16 + m16) * 72 + ks * 32 + kq * 8];
#pragma unroll
      for (int jt = 0; jt < 8; jt++)
        bfr[jt] = *(const bf16x8*)&Ks[(jt * 16 + m16) * 72 + ks * 32 + kq * 8];
#pragma unroll
      for (int it = 0; it < 2; it++)
#pragma unroll
        for (int jt = 0; jt < 8; jt++) acc[it][jt] = MFMA16(af[it], bfr[jt], acc[it][jt]);
    }
  }

  const float sc = 1.f / 128.f;  // dh^-0.5 * H^-0.5
#pragma unroll
  for (int it = 0; it < 2; it++)
#pragma unroll
    for (int jt = 0; jt < 8; jt++)
#pragma unroll
      for (int r = 0; r < 4; r++) {
        int i = i0 + ioff + it * 16 + kq * 4 + r;
        int j = j0 + jt * 16 + m16;
        atomicAdd(&dots[(size_t)head * 65536 + i * 256 + j], acc[it][jt][r] * sc);
      }
}

// ---------------------------------------------------------------- pair bias: LN + @W_pair (wave per ij)
__global__ void __launch_bounds__(256) k_pb(const float* __restrict__ pb,
                                            const float* __restrict__ g,
                                            const float* __restrict__ bb,
                                            const float* __restrict__ Wp,
                                            float* __restrict__ dots) {
  __shared__ float sn[4][128];
  const int tid = threadIdx.x, lane = tid & 63, wv = tid >> 6;
  const size_t ij = (size_t)blockIdx.x * 4 + wv;
  const float2 xv = *(const float2*)(pb + ij * 128 + lane * 2);

  float s = xv.x + xv.y;
#pragma unroll
  for (int o = 1; o < 64; o <<= 1) s += __shfl_xor(s, o);
  const float mu = s * (1.f / 128.f);
  const float d0 = xv.x - mu, d1 = xv.y - mu;
  float s2 = d0 * d0 + d1 * d1;
#pragma unroll
  for (int o = 1; o < 64; o <<= 1) s2 += __shfl_xor(s2, o);
  const float inv = rsqrtf(s2 * (1.f / 128.f) + 1e-5f);

  sn[wv][lane * 2 + 0] = d0 * inv * g[lane * 2 + 0] + bb[lane * 2 + 0];
  sn[wv][lane * 2 + 1] = d1 * inv * g[lane * 2 + 1] + bb[lane * 2 + 1];

  const int h = lane & 7, gp = lane >> 3;  // 8 heads x 8 p-groups of 16
  float a = 0.f;
#pragma unroll
  for (int p0 = 0; p0 < 16; p0++) {
    const int p = gp * 16 + p0;
    a += sn[wv][p] * Wp[p * 8 + h];
  }
  a += __shfl_xor(a, 8);
  a += __shfl_xor(a, 16);
  a += __shfl_xor(a, 32);
  if (lane < 8) dots[(size_t)h * 65536 + ij] += a;
}

// ---------------------------------------------------------------- softmax -> normalized bf16 P
__global__ void __launch_bounds__(256) k_softmax(const float* __restrict__ dots,
                                                 bf16* __restrict__ P) {
  __shared__ float red[4];
  const int i = blockIdx.x, head = blockIdx.y, t = threadIdx.x;
  const size_t base = (size_t)head * 65536 + i * 256;
  const float e = __expf(dots[base + t]);
  float s = e;
#pragma unroll
  for (int o = 1; o < 64; o <<= 1) s += __shfl_xor(s, o);
  if ((t & 63) == 0) red[t >> 6] = s;
  __syncthreads();
  const float S = red[0] + red[1] + red[2] + red[3];
  P[base + t] = __float2bfloat16(e / S);
}

// ---------------------------------------------------------------- height PV (MFMA) + fused proj
// grid (HH, NHEADS), block 256 = 4 waves (i-strip 64).
// LDS: Vt[64][264] @0 (33792) | Wtr[64][72] @36864 (9216); Ot[wave][64][72] @0 reuses Vt. Total 46080.
__global__ void __launch_bounds__(256, 2)
k_h_pv(const bf16* __restrict__ P, const bf16* __restrict__ v,
       const float* __restrict__ Wout, float* __restrict__ out) {
  __shared__ __align__(16) char smem[46080];
  bf16* Vt  = (bf16*)smem;
  bf16* Wtr = (bf16*)(smem + 36864);
  const int r = blockIdx.x, head = blockIdx.y;
  const int tid = threadIdx.x, lane = tid & 63, wv = tid >> 6;
  bf16* Ot = (bf16*)(smem + (size_t)wv * 9216);
  const int m16 = lane & 15, kq = lane >> 4;

  {
    const bf16* src = v + ((size_t)(r * 256 + tid) * 512 + head * 64);
    uint4 rr[8];
#pragma unroll
    for (int c = 0; c < 8; c++) rr[c] = ((const uint4*)src)[c];
#pragma unroll
    for (int c = 0; c < 8; c++) {
      const bf16* e = (const bf16*)&rr[c];
#pragma unroll
      for (int t = 0; t < 8; t++) Vt[(c * 8 + t) * 264 + tid] = e[t];
    }
  }
#pragma unroll
  for (int s = 0; s < 16; s++) {
    int idx = s * 256 + tid;
    int d = idx >> 6, c = idx & 63;
    Wtr[c * 72 + d] = __float2bfloat16(Wout[(head * 64 + d) * 64 + c]);
  }

  const bf16* Pb = P + (size_t)head * 65536;
  const int i0 = wv * 64;
  auto loadP = [&](int ks, bf16x8 pf[4]) {
#pragma unroll
    for (int it = 0; it < 4; it++)
      pf[it] = *(const bf16x8*)(Pb + (size_t)(i0 + it * 16 + m16) * 256 + ks * 32 + kq * 8);
  };
  bf16x8 pcur[4];
  loadP(0, pcur);  // global prefetch before barrier
  __syncthreads();

  f32x4 acc[4][4];
#pragma unroll
  for (int a = 0; a < 4; a++)
#pragma unroll
    for (int b = 0; b < 4; b++) acc[a][b] = (f32x4){0.f, 0.f, 0.f, 0.f};

#pragma unroll 1
  for (int ks = 0; ks < 8; ks++) {
    bf16x8 pnext[4];
    if (ks < 7) loadP(ks + 1, pnext);
    bf16x8 vf[4];
#pragma unroll
    for (int dt = 0; dt < 4; dt++)
      vf[dt] = *(const bf16x8*)&Vt[(dt * 16 + m16) * 264 + ks * 32 + kq * 8];
#pragma unroll
    for (int it = 0; it < 4; it++)
#pragma unroll
      for (int dt = 0; dt < 4; dt++) acc[it][dt] = MFMA16(pcur[it], vf[dt], acc[it][dt]);
    if (ks < 7) {
#pragma unroll
      for (int it = 0; it < 4; it++) pcur[it] = pnext[it];
    }
  }
  __syncthreads();  // Vt dead -> Ot
#pragma unroll
  for (int it = 0; it < 4; it++)
#pragma unroll
    for (int dt = 0; dt < 4; dt++)
#pragma unroll
      for (int r2 = 0; r2 < 4; r2++)
        Ot[(it * 16 + kq * 4 + r2) * 72 + dt * 16 + m16] = __float2bfloat16(acc[it][dt][r2]);

  bf16x8 of[4][2], wf[4][2];
#pragma unroll
  for (int it = 0; it < 4; it++) {
    of[it][0] = *(const bf16x8*)&Ot[(it * 16 + m16) * 72 + kq * 8];
    of[it][1] = *(const bf16x8*)&Ot[(it * 16 + m16) * 72 + 32 + kq * 8];
  }
#pragma unroll
  for (int ct = 0; ct < 4; ct++) {
    wf[ct][0] = *(const bf16x8*)&Wtr[(ct * 16 + m16) * 72 + kq * 8];
    wf[ct][1] = *(const bf16x8*)&Wtr[(ct * 16 + m16) * 72 + 32 + kq * 8];
  }
#pragma unroll
  for (int it = 0; it < 4; it++)
#pragma unroll
    for (int ct = 0; ct < 4; ct++) {
      f32x4 c2 = (f32x4){0.f, 0.f, 0.f, 0.f};
      c2 = MFMA16(of[it][0], wf[ct][0], c2);
      c2 = MFMA16(of[it][1], wf[ct][1], c2);
#pragma unroll
      for (int r2 = 0; r2 < 4; r2++) {
        int i = i0 + it * 16 + kq * 4 + r2;  // = w position
        atomicAdd(&out[(size_t)(r * 256 + i) * 64 + ct * 16 + m16], 0.5f * c2[r2]);
      }
    }
}

// ================================================================ launch
extern "C" void kernel_launch(void* const* d_in, const int* in_sizes, int n_in,
                              void* d_out, int out_size, void* d_ws, size_t ws_size,
                              hipStream_t stream) {
  const float* x      = (const float*)d_in[0];
  const float* pair   = (const float*)d_in[1];
  const float* Wq_w   = (const float*)d_in[2];
  const float* Wkv_w  = (const float*)d_in[3];
  const float* Wout_w = (const float*)d_in[4];
  const float* bout_w = (const float*)d_in[5];
  const float* Wq_h   = (const float*)d_in[6];
  const float* Wkv_h  = (const float*)d_in[7];
  const float* Wout_h = (const float*)d_in[8];
  const float* bout_h = (const float*)d_in[9];
  const float* ln_g   = (const float*)d_in[10];
  const float* ln_b   = (const float*)d_in[11];
  const float* W_pair = (const float*)d_in[12];
  float* out = (float*)d_out;

  const size_t NE = (size_t)NROWS * 512;
  bf16* q = (bf16*)d_ws;
  bf16* k = q + NE;
  bf16* v = k + NE;
  float* dots = (float*)(v + NE);
  bf16* P = q;  // alias: q is dead after k_dots

  k_init_out<<<NROWS * 64 / 256, 256, 0, stream>>>(bout_w, bout_h, out);

  // -------- width attention --------
  k_qkv<<<dim3(NROWS / 16, 6), 256, 0, stream>>>(x, Wq_w, Wkv_w, q, k, v);
  k_width_attn<<<dim3(WW, NHEADS), 256, 0, stream>>>(q, k, v, Wout_w, out);

  // -------- height attention --------
  k_qkv<<<dim3(NROWS / 16, 6), 256, 0, stream>>>(x, Wq_h, Wkv_h, q, k, v);
  hipMemsetAsync(dots, 0, (size_t)8 * 65536 * sizeof(float), stream);
  k_dots<<<dim3(4, NHEADS, 16), 256, 0, stream>>>(q, k, dots);
  k_pb<<<65536 / 4, 256, 0, stream>>>(pair, ln_g, ln_b, W_pair, dots);
  k_softmax<<<dim3(256, NHEADS), 256, 0, stream>>>(dots, P);
  k_h_pv<<<dim3(HH, NHEADS), 256, 0, stream>>>(P, v, Wout_h, out);
}

// Round 3
// 670.054 us; speedup vs baseline: 7.6074x; 1.5017x over previous
//
#include <hip/hip_runtime.h>
#include <hip/hip_bf16.h>

typedef __hip_bfloat16 bf16;
typedef __attribute__((ext_vector_type(8))) short bf16x8;
typedef __attribute__((ext_vector_type(4))) float f32x4;

#define MFMA16(a, b, c) __builtin_amdgcn_mfma_f32_16x16x32_bf16(a, b, c, 0, 0, 0)

// Problem constants (B=1)
#define HH 256
#define WW 256
#define DD 64
#define PP 128
#define NHEADS 8
#define DHEAD 64
#define NROWS 65536

// ws layout: q | k | v (bf16, 67MB each) | dots (f32 2MB)  = 203.4 MB
// Wt_w / Wt_h (bf16 [1536][64], 196KB each) alias the dots region (dead until memset).
// P_bf16 (1 MB) aliases q (q is dead once k_dots finishes).

// MFMA fragment conventions (verified m89/m91/m120):
//   A-frag: lane l holds A[m = l&15][k = (l>>4)*8 + t], t=0..7  (contiguous k)
//   B-frag: lane l holds B[n = l&15][k = (l>>4)*8 + t]          (contiguous k)
//   C/D   : lane l, reg r -> (col = l&15, row = (l>>4)*4 + r)
//   D[m][n] = sum_k A[m][k]*B[n][k]

__device__ __forceinline__ bf16x8 cvt8(const float* f) {
  bf16x8 r;
  bf16* h = (bf16*)&r;
#pragma unroll
  for (int i = 0; i < 8; i++) h[i] = __float2bfloat16(f[i]);
  return r;
}

// ---------------------------------------------------------------- init output
__global__ void __launch_bounds__(256) k_init_out(const float* __restrict__ bw,
                                                  const float* __restrict__ bh,
                                                  float* __restrict__ out) {
  int idx = blockIdx.x * 256 + threadIdx.x;
  out[idx] = 0.5f * (bw[idx & 63] + bh[idx & 63]);
}

// ---------------------------------------------------------------- W transpose: f32 [64][1536] -> bf16 [1536][64]
// both phases in one kernel. grid 768, block 256.
__global__ void __launch_bounds__(256) k_wt(const float* __restrict__ Wq_w,
                                            const float* __restrict__ Wkv_w,
                                            const float* __restrict__ Wq_h,
                                            const float* __restrict__ Wkv_h,
                                            bf16* __restrict__ Wt_w,
                                            bf16* __restrict__ Wt_h) {
  int idx = blockIdx.x * 256 + threadIdx.x;  // [0, 2*98304)
  const float* Wq = Wq_w;
  const float* Wkv = Wkv_w;
  bf16* dst = Wt_w;
  if (idx >= 98304) { idx -= 98304; Wq = Wq_h; Wkv = Wkv_h; dst = Wt_h; }
  const int k = idx / 1536, c = idx - k * 1536;  // read coalesced along c
  const float val = (c < 512) ? Wq[k * 512 + c] : Wkv[k * 1024 + (c - 512)];
  dst[(size_t)c * 64 + k] = __float2bfloat16(val);
}

// ---------------------------------------------------------------- QKV via MFMA
// grid 1024 (64-row strips), block 256 = 4 waves (16 rows each). No LDS, no barriers.
__global__ void __launch_bounds__(256) k_qkv_mfma(const float* __restrict__ x,
                                                  const bf16* __restrict__ Wt,  // [1536][64]
                                                  bf16* __restrict__ q,
                                                  bf16* __restrict__ kk,
                                                  bf16* __restrict__ v) {
  const int tid = threadIdx.x, lane = tid & 63, wv = tid >> 6;
  const int m16 = lane & 15, kq = lane >> 4;
  const int rowA = blockIdx.x * 64 + wv * 16 + m16;   // A-frag row (m)
  const int rowC0 = blockIdx.x * 64 + wv * 16 + kq * 4;  // C-frag first row

  // A-frags in registers: X[rowA][k], k = kh*32 + kq*8 .. +7  (f32 -> bf16)
  const float* xr = x + (size_t)rowA * 64;
  float xf[8];
  bf16x8 af[2];
  *(float4*)&xf[0] = *(const float4*)(xr + kq * 8);
  *(float4*)&xf[4] = *(const float4*)(xr + kq * 8 + 4);
  af[0] = cvt8(xf);
  *(float4*)&xf[0] = *(const float4*)(xr + 32 + kq * 8);
  *(float4*)&xf[4] = *(const float4*)(xr + 32 + kq * 8 + 4);
  af[1] = cvt8(xf);

#pragma unroll 1
  for (int cg = 0; cg < 12; cg++) {  // 128-col groups; 0-3 -> q, 4-7 -> k, 8-11 -> v
    bf16* dst = (cg < 4) ? q : (cg < 8) ? kk : v;
    const int cbase = (cg & 3) * 128;
#pragma unroll
    for (int ct = 0; ct < 8; ct++) {
      const bf16* wp = Wt + (size_t)(cg * 128 + ct * 16 + m16) * 64 + kq * 8;
      const bf16x8 b0 = *(const bf16x8*)wp;
      const bf16x8 b1 = *(const bf16x8*)(wp + 32);
      f32x4 a = (f32x4){0.f, 0.f, 0.f, 0.f};
      a = MFMA16(af[0], b0, a);
      a = MFMA16(af[1], b1, a);
      const int cloc = cbase + ct * 16 + m16;
#pragma unroll
      for (int r = 0; r < 4; r++)
        dst[(size_t)(rowC0 + r) * 512 + cloc] = __float2bfloat16(a[r]);
    }
  }
}

// ---------------------------------------------------------------- width attention (MFMA) + fused proj
// grid (WW, NHEADS), block 256 = 4 waves; wave handles 64-row Q strip.
// LDS: Vt[64][264] @0 (33792) | Ps[wave][64][40] @33792 (4x5120) | Wtr[64][72] @54272 (9216)
//      Ot[wave][64][72] @0 (4x9216=36864) reuses Vt+Ps after barrier. Total 63488.
__global__ void __launch_bounds__(256, 2)
k_width_attn(const bf16* __restrict__ q, const bf16* __restrict__ kk,
             const bf16* __restrict__ v, const float* __restrict__ Wout,
             float* __restrict__ out) {
  __shared__ __align__(16) char smem[63488];
  bf16* Vt  = (bf16*)smem;
  bf16* Wtr = (bf16*)(smem + 54272);
  const int w = blockIdx.x, head = blockIdx.y;
  const int tid = threadIdx.x, lane = tid & 63, wv = tid >> 6;
  bf16* Ps = (bf16*)(smem + 33792 + wv * 5120);
  bf16* Ot = (bf16*)(smem + (size_t)wv * 9216);
  const int m16 = lane & 15, kq = lane >> 4;

  // stage Vt[d][j] = V[j][d]
  {
    const bf16* src = v + ((size_t)(tid * 256 + w) * 512 + head * 64);
    uint4 rr[8];
#pragma unroll
    for (int c = 0; c < 8; c++) rr[c] = ((const uint4*)src)[c];
#pragma unroll
    for (int c = 0; c < 8; c++) {
      const bf16* e = (const bf16*)&rr[c];
#pragma unroll
      for (int t = 0; t < 8; t++) Vt[(c * 8 + t) * 264 + tid] = e[t];
    }
  }
  // stage Wtr[c][d] = Wout[head*64+d][c]
#pragma unroll
  for (int s = 0; s < 16; s++) {
    int idx = s * 256 + tid;
    int d = idx >> 6, c = idx & 63;
    Wtr[c * 72 + d] = __float2bfloat16(Wout[(head * 64 + d) * 64 + c]);
  }
  // preload Q A-frags
  bf16x8 qf[4][2];
  const int i0 = wv * 64;
#pragma unroll
  for (int it = 0; it < 4; it++) {
    const bf16* b = q + ((size_t)((i0 + it * 16 + m16) * 256 + w) * 512 + head * 64 + kq * 8);
    qf[it][0] = *(const bf16x8*)b;
    qf[it][1] = *(const bf16x8*)(b + 32);
  }
  __syncthreads();

  f32x4 acc[4][4];
#pragma unroll
  for (int a = 0; a < 4; a++)
#pragma unroll
    for (int b = 0; b < 4; b++) acc[a][b] = (f32x4){0.f, 0.f, 0.f, 0.f};
  float rsum[4][4];
#pragma unroll
  for (int a = 0; a < 4; a++)
#pragma unroll
    for (int r = 0; r < 4; r++) rsum[a][r] = 0.f;

  auto loadK = [&](int jc, bf16x8 kf[2][2]) {
#pragma unroll
    for (int jt = 0; jt < 2; jt++) {
      const bf16* b = kk + ((size_t)((jc * 32 + jt * 16 + m16) * 256 + w) * 512 + head * 64 + kq * 8);
      kf[jt][0] = *(const bf16x8*)b;
      kf[jt][1] = *(const bf16x8*)(b + 32);
    }
  };
  bf16x8 kcur[2][2];
  loadK(0, kcur);

#pragma unroll 1
  for (int jc = 0; jc < 8; jc++) {
    bf16x8 knext[2][2];
    if (jc < 7) loadK(jc + 1, knext);
#pragma unroll
    for (int it = 0; it < 4; it++)
#pragma unroll
      for (int jt = 0; jt < 2; jt++) {
        f32x4 s = (f32x4){0.f, 0.f, 0.f, 0.f};
        s = MFMA16(qf[it][0], kcur[jt][0], s);
        s = MFMA16(qf[it][1], kcur[jt][1], s);
#pragma unroll
        for (int r = 0; r < 4; r++) {
          float p = __expf(s[r] * 0.125f);
          rsum[it][r] += p;
          Ps[(it * 16 + kq * 4 + r) * 40 + jt * 16 + m16] = __float2bfloat16(p);
        }
      }
    bf16x8 pf[4], vf[4];
#pragma unroll
    for (int it = 0; it < 4; it++)
      pf[it] = *(const bf16x8*)&Ps[(it * 16 + m16) * 40 + kq * 8];
#pragma unroll
    for (int dt = 0; dt < 4; dt++)
      vf[dt] = *(const bf16x8*)&Vt[(dt * 16 + m16) * 264 + jc * 32 + kq * 8];
#pragma unroll
    for (int it = 0; it < 4; it++)
#pragma unroll
      for (int dt = 0; dt < 4; dt++) acc[it][dt] = MFMA16(pf[it], vf[dt], acc[it][dt]);
    if (jc < 7) {
#pragma unroll
      for (int jt = 0; jt < 2; jt++) {
        kcur[jt][0] = knext[jt][0];
        kcur[jt][1] = knext[jt][1];
      }
    }
  }

#pragma unroll
  for (int it = 0; it < 4; it++)
#pragma unroll
    for (int r = 0; r < 4; r++) {
      float s = rsum[it][r];
      s += __shfl_xor(s, 1); s += __shfl_xor(s, 2);
      s += __shfl_xor(s, 4); s += __shfl_xor(s, 8);
      rsum[it][r] = 1.f / s;
    }
  __syncthreads();
#pragma unroll
  for (int it = 0; it < 4; it++)
#pragma unroll
    for (int dt = 0; dt < 4; dt++)
#pragma unroll
      for (int r = 0; r < 4; r++)
        Ot[(it * 16 + kq * 4 + r) * 72 + dt * 16 + m16] =
            __float2bfloat16(acc[it][dt][r] * rsum[it][r]);
  bf16x8 of[4][2], wf[4][2];
#pragma unroll
  for (int it = 0; it < 4; it++) {
    of[it][0] = *(const bf16x8*)&Ot[(it * 16 + m16) * 72 + kq * 8];
    of[it][1] = *(const bf16x8*)&Ot[(it * 16 + m16) * 72 + 32 + kq * 8];
  }
#pragma unroll
  for (int ct = 0; ct < 4; ct++) {
    wf[ct][0] = *(const bf16x8*)&Wtr[(ct * 16 + m16) * 72 + kq * 8];
    wf[ct][1] = *(const bf16x8*)&Wtr[(ct * 16 + m16) * 72 + 32 + kq * 8];
  }
#pragma unroll
  for (int it = 0; it < 4; it++)
#pragma unroll
    for (int ct = 0; ct < 4; ct++) {
      f32x4 c2 = (f32x4){0.f, 0.f, 0.f, 0.f};
      c2 = MFMA16(of[it][0], wf[ct][0], c2);
      c2 = MFMA16(of[it][1], wf[ct][1], c2);
#pragma unroll
      for (int r = 0; r < 4; r++) {
        int i = i0 + it * 16 + kq * 4 + r;
        atomicAdd(&out[(size_t)(i * 256 + w) * 64 + ct * 16 + m16], 0.5f * c2[r]);
      }
    }
}

// ---------------------------------------------------------------- height tied dots (MFMA)
// grid (4 tiles of 128x128, 8 heads, 16 r-chunks of 16), block 256 = 4 waves
__global__ void __launch_bounds__(256, 2)
k_dots(const bf16* __restrict__ q, const bf16* __restrict__ kk, float* __restrict__ dots) {
  __shared__ __align__(16) char smem[36864];
  bf16* Qs = (bf16*)smem;
  bf16* Ks = (bf16*)(smem + 18432);
  const int tile = blockIdx.x, head = blockIdx.y, rc = blockIdx.z;
  const int i0 = (tile >> 1) * 128, j0 = (tile & 1) * 128;
  const int tid = threadIdx.x, lane = tid & 63, wv = tid >> 6;
  const int m16 = lane & 15, kq = lane >> 4;
  const int ioff = wv * 32;

  f32x4 acc[2][8];
#pragma unroll
  for (int a = 0; a < 2; a++)
#pragma unroll
    for (int b = 0; b < 8; b++) acc[a][b] = (f32x4){0.f, 0.f, 0.f, 0.f};

#pragma unroll 1
  for (int rr = 0; rr < 16; rr++) {
    const int rrow = rc * 16 + rr;
    __syncthreads();
#pragma unroll
    for (int s = 0; s < 4; s++) {
      int idx = s * 256 + tid;
      int row = idx >> 3, ch = idx & 7;
      *(uint4*)&Qs[row * 72 + ch * 8] =
          *(const uint4*)(q + ((size_t)(rrow * 256 + i0 + row) * 512 + head * 64 + ch * 8));
      *(uint4*)&Ks[row * 72 + ch * 8] =
          *(const uint4*)(kk + ((size_t)(rrow * 256 + j0 + row) * 512 + head * 64 + ch * 8));
    }
    __syncthreads();
#pragma unroll
    for (int ks = 0; ks < 2; ks++) {
      bf16x8 af[2], bfr[8];
#pragma unroll
      for (int it = 0; it < 2; it++)
        af[it] = *(const bf16x8*)&Qs[(ioff + it * 16 + m16) * 72 + ks * 32 + kq * 8];
#pragma unroll
      for (int jt = 0; jt < 8; jt++)
        bfr[jt] = *(const bf16x8*)&Ks[(jt * 16 + m16) * 72 + ks * 32 + kq * 8];
#pragma unroll
      for (int it = 0; it < 2; it++)
#pragma unroll
        for (int jt = 0; jt < 8; jt++) acc[it][jt] = MFMA16(af[it], bfr[jt], acc[it][jt]);
    }
  }

  const float sc = 1.f / 128.f;
#pragma unroll
  for (int it = 0; it < 2; it++)
#pragma unroll
    for (int jt = 0; jt < 8; jt++)
#pragma unroll
      for (int r = 0; r < 4; r++) {
        int i = i0 + ioff + it * 16 + kq * 4 + r;
        int j = j0 + jt * 16 + m16;
        atomicAdd(&dots[(size_t)head * 65536 + i * 256 + j], acc[it][jt][r] * sc);
      }
}

// ---------------------------------------------------------------- pair bias: LN + @W_pair (wave per ij)
__global__ void __launch_bounds__(256) k_pb(const float* __restrict__ pb,
                                            const float* __restrict__ g,
                                            const float* __restrict__ bb,
                                            const float* __restrict__ Wp,
                                            float* __restrict__ dots) {
  __shared__ float sn[4][128];
  const int tid = threadIdx.x, lane = tid & 63, wv = tid >> 6;
  const size_t ij = (size_t)blockIdx.x * 4 + wv;
  const float2 xv = *(const float2*)(pb + ij * 128 + lane * 2);

  float s = xv.x + xv.y;
#pragma unroll
  for (int o = 1; o < 64; o <<= 1) s += __shfl_xor(s, o);
  const float mu = s * (1.f / 128.f);
  const float d0 = xv.x - mu, d1 = xv.y - mu;
  float s2 = d0 * d0 + d1 * d1;
#pragma unroll
  for (int o = 1; o < 64; o <<= 1) s2 += __shfl_xor(s2, o);
  const float inv = rsqrtf(s2 * (1.f / 128.f) + 1e-5f);

  sn[wv][lane * 2 + 0] = d0 * inv * g[lane * 2 + 0] + bb[lane * 2 + 0];
  sn[wv][lane * 2 + 1] = d1 * inv * g[lane * 2 + 1] + bb[lane * 2 + 1];

  const int h = lane & 7, gp = lane >> 3;
  float a = 0.f;
#pragma unroll
  for (int p0 = 0; p0 < 16; p0++) {
    const int p = gp * 16 + p0;
    a += sn[wv][p] * Wp[p * 8 + h];
  }
  a += __shfl_xor(a, 8);
  a += __shfl_xor(a, 16);
  a += __shfl_xor(a, 32);
  if (lane < 8) dots[(size_t)h * 65536 + ij] += a;
}

// ---------------------------------------------------------------- softmax -> normalized bf16 P
__global__ void __launch_bounds__(256) k_softmax(const float* __restrict__ dots,
                                                 bf16* __restrict__ P) {
  __shared__ float red[4];
  const int i = blockIdx.x, head = blockIdx.y, t = threadIdx.x;
  const size_t base = (size_t)head * 65536 + i * 256;
  const float e = __expf(dots[base + t]);
  float s = e;
#pragma unroll
  for (int o = 1; o < 64; o <<= 1) s += __shfl_xor(s, o);
  if ((t & 63) == 0) red[t >> 6] = s;
  __syncthreads();
  const float S = red[0] + red[1] + red[2] + red[3];
  P[base + t] = __float2bfloat16(e / S);
}

// ---------------------------------------------------------------- height PV (MFMA) + fused proj
__global__ void __launch_bounds__(256, 2)
k_h_pv(const bf16* __restrict__ P, const bf16* __restrict__ v,
       const float* __restrict__ Wout, float* __restrict__ out) {
  __shared__ __align__(16) char smem[46080];
  bf16* Vt  = (bf16*)smem;
  bf16* Wtr = (bf16*)(smem + 36864);
  const int r = blockIdx.x, head = blockIdx.y;
  const int tid = threadIdx.x, lane = tid & 63, wv = tid >> 6;
  bf16* Ot = (bf16*)(smem + (size_t)wv * 9216);
  const int m16 = lane & 15, kq = lane >> 4;

  {
    const bf16* src = v + ((size_t)(r * 256 + tid) * 512 + head * 64);
    uint4 rr[8];
#pragma unroll
    for (int c = 0; c < 8; c++) rr[c] = ((const uint4*)src)[c];
#pragma unroll
    for (int c = 0; c < 8; c++) {
      const bf16* e = (const bf16*)&rr[c];
#pragma unroll
      for (int t = 0; t < 8; t++) Vt[(c * 8 + t) * 264 + tid] = e[t];
    }
  }
#pragma unroll
  for (int s = 0; s < 16; s++) {
    int idx = s * 256 + tid;
    int d = idx >> 6, c = idx & 63;
    Wtr[c * 72 + d] = __float2bfloat16(Wout[(head * 64 + d) * 64 + c]);
  }

  const bf16* Pb = P + (size_t)head * 65536;
  const int i0 = wv * 64;
  auto loadP = [&](int ks, bf16x8 pf[4]) {
#pragma unroll
    for (int it = 0; it < 4; it++)
      pf[it] = *(const bf16x8*)(Pb + (size_t)(i0 + it * 16 + m16) * 256 + ks * 32 + kq * 8);
  };
  bf16x8 pcur[4];
  loadP(0, pcur);
  __syncthreads();

  f32x4 acc[4][4];
#pragma unroll
  for (int a = 0; a < 4; a++)
#pragma unroll
    for (int b = 0; b < 4; b++) acc[a][b] = (f32x4){0.f, 0.f, 0.f, 0.f};

#pragma unroll 1
  for (int ks = 0; ks < 8; ks++) {
    bf16x8 pnext[4];
    if (ks < 7) loadP(ks + 1, pnext);
    bf16x8 vf[4];
#pragma unroll
    for (int dt = 0; dt < 4; dt++)
      vf[dt] = *(const bf16x8*)&Vt[(dt * 16 + m16) * 264 + ks * 32 + kq * 8];
#pragma unroll
    for (int it = 0; it < 4; it++)
#pragma unroll
      for (int dt = 0; dt < 4; dt++) acc[it][dt] = MFMA16(pcur[it], vf[dt], acc[it][dt]);
    if (ks < 7) {
#pragma unroll
      for (int it = 0; it < 4; it++) pcur[it] = pnext[it];
    }
  }
  __syncthreads();
#pragma unroll
  for (int it = 0; it < 4; it++)
#pragma unroll
    for (int dt = 0; dt < 4; dt++)
#pragma unroll
      for (int r2 = 0; r2 < 4; r2++)
        Ot[(it * 16 + kq * 4 + r2) * 72 + dt * 16 + m16] = __float2bfloat16(acc[it][dt][r2]);

  bf16x8 of[4][2], wf[4][2];
#pragma unroll
  for (int it = 0; it < 4; it++) {
    of[it][0] = *(const bf16x8*)&Ot[(it * 16 + m16) * 72 + kq * 8];
    of[it][1] = *(const bf16x8*)&Ot[(it * 16 + m16) * 72 + 32 + kq * 8];
  }
#pragma unroll
  for (int ct = 0; ct < 4; ct++) {
    wf[ct][0] = *(const bf16x8*)&Wtr[(ct * 16 + m16) * 72 + kq * 8];
    wf[ct][1] = *(const bf16x8*)&Wtr[(ct * 16 + m16) * 72 + 32 + kq * 8];
  }
#pragma unroll
  for (int it = 0; it < 4; it++)
#pragma unroll
    for (int ct = 0; ct < 4; ct++) {
      f32x4 c2 = (f32x4){0.f, 0.f, 0.f, 0.f};
      c2 = MFMA16(of[it][0], wf[ct][0], c2);
      c2 = MFMA16(of[it][1], wf[ct][1], c2);
#pragma unroll
      for (int r2 = 0; r2 < 4; r2++) {
        int i = i0 + it * 16 + kq * 4 + r2;
        atomicAdd(&out[(size_t)(r * 256 + i) * 64 + ct * 16 + m16], 0.5f * c2[r2]);
      }
    }
}

// ================================================================ launch
extern "C" void kernel_launch(void* const* d_in, const int* in_sizes, int n_in,
                              void* d_out, int out_size, void* d_ws, size_t ws_size,
                              hipStream_t stream) {
  const float* x      = (const float*)d_in[0];
  const float* pair   = (const float*)d_in[1];
  const float* Wq_w   = (const float*)d_in[2];
  const float* Wkv_w  = (const float*)d_in[3];
  const float* Wout_w = (const float*)d_in[4];
  const float* bout_w = (const float*)d_in[5];
  const float* Wq_h   = (const float*)d_in[6];
  const float* Wkv_h  = (const float*)d_in[7];
  const float* Wout_h = (const float*)d_in[8];
  const float* bout_h = (const float*)d_in[9];
  const float* ln_g   = (const float*)d_in[10];
  const float* ln_b   = (const float*)d_in[11];
  const float* W_pair = (const float*)d_in[12];
  float* out = (float*)d_out;

  const size_t NE = (size_t)NROWS * 512;
  bf16* q = (bf16*)d_ws;
  bf16* k = q + NE;
  bf16* v = k + NE;
  float* dots = (float*)(v + NE);
  bf16* P = q;                      // alias: q dead after k_dots
  bf16* Wt_w = (bf16*)dots;         // alias: dots region dead until memset
  bf16* Wt_h = Wt_w + 98304;

  k_wt<<<768, 256, 0, stream>>>(Wq_w, Wkv_w, Wq_h, Wkv_h, Wt_w, Wt_h);
  k_init_out<<<NROWS * 64 / 256, 256, 0, stream>>>(bout_w, bout_h, out);

  // -------- width attention --------
  k_qkv_mfma<<<1024, 256, 0, stream>>>(x, Wt_w, q, k, v);
  k_width_attn<<<dim3(WW, NHEADS), 256, 0, stream>>>(q, k, v, Wout_w, out);

  // -------- height attention --------
  k_qkv_mfma<<<1024, 256, 0, stream>>>(x, Wt_h, q, k, v);
  hipMemsetAsync(dots, 0, (size_t)8 * 65536 * sizeof(float), stream);
  k_dots<<<dim3(4, NHEADS, 16), 256, 0, stream>>>(q, k, dots);
  k_pb<<<65536 / 4, 256, 0, stream>>>(pair, ln_g, ln_b, W_pair, dots);
  k_softmax<<<dim3(256, NHEADS), 256, 0, stream>>>(dots, P);
  k_h_pv<<<dim3(HH, NHEADS), 256, 0, stream>>>(P, v, Wout_h, out);
}

// Round 4
// 664.560 us; speedup vs baseline: 7.6702x; 1.0083x over previous
//
#include <hip/hip_runtime.h>
#include <hip/hip_bf16.h>

typedef __hip_bfloat16 bf16;
typedef __attribute__((ext_vector_type(8))) short bf16x8;
typedef __attribute__((ext_vector_type(4))) float f32x4;

#define MFMA16(a, b, c) __builtin_amdgcn_mfma_f32_16x16x32_bf16(a, b, c, 0, 0, 0)

// Problem constants (B=1)
#define HH 256
#define WW 256
#define DD 64
#define PP 128
#define NHEADS 8
#define DHEAD 64
#define NROWS 65536

// ws layout: q | k | v (bf16, 67MB each) | dots (f32 2MB)  = 203.4 MB
// Wt_w / Wt_h alias dots region (dead until memset). P aliases q (dead after k_dots).
// Width phase stores q/k/v in W-MAJOR rows (w*256+h) so k_width_attn streams
// contiguous 256KB slabs per w. Height phase keeps h-major rows.

// MFMA fragment conventions (verified m89/m91/m120):
//   A-frag: lane l holds A[m = l&15][k = (l>>4)*8 + t], t=0..7
//   B-frag: lane l holds B[n = l&15][k = (l>>4)*8 + t]
//   C/D   : lane l, reg r -> (col = l&15, row = (l>>4)*4 + r)
//   D[m][n] = sum_k A[m][k]*B[n][k]

__device__ __forceinline__ bf16x8 cvt8(const float* f) {
  bf16x8 r;
  bf16* h = (bf16*)&r;
#pragma unroll
  for (int i = 0; i < 8; i++) h[i] = __float2bfloat16(f[i]);
  return r;
}

// ---------------------------------------------------------------- init output
__global__ void __launch_bounds__(256) k_init_out(const float* __restrict__ bw,
                                                  const float* __restrict__ bh,
                                                  float* __restrict__ out) {
  int idx = blockIdx.x * 256 + threadIdx.x;
  out[idx] = 0.5f * (bw[idx & 63] + bh[idx & 63]);
}

// ---------------------------------------------------------------- W transpose
__global__ void __launch_bounds__(256) k_wt(const float* __restrict__ Wq_w,
                                            const float* __restrict__ Wkv_w,
                                            const float* __restrict__ Wq_h,
                                            const float* __restrict__ Wkv_h,
                                            bf16* __restrict__ Wt_w,
                                            bf16* __restrict__ Wt_h) {
  int idx = blockIdx.x * 256 + threadIdx.x;
  const float* Wq = Wq_w;
  const float* Wkv = Wkv_w;
  bf16* dst = Wt_w;
  if (idx >= 98304) { idx -= 98304; Wq = Wq_h; Wkv = Wkv_h; dst = Wt_h; }
  const int k = idx / 1536, c = idx - k * 1536;
  const float val = (c < 512) ? Wq[k * 512 + c] : Wkv[k * 1024 + (c - 512)];
  dst[(size_t)c * 64 + k] = __float2bfloat16(val);
}

// ---------------------------------------------------------------- QKV via MFMA
// swap=1 -> write rows w-major (w*256+h) for the width phase.
__global__ void __launch_bounds__(256) k_qkv_mfma(const float* __restrict__ x,
                                                  const bf16* __restrict__ Wt,
                                                  bf16* __restrict__ q,
                                                  bf16* __restrict__ kk,
                                                  bf16* __restrict__ v,
                                                  int swap) {
  const int tid = threadIdx.x, lane = tid & 63, wv = tid >> 6;
  const int m16 = lane & 15, kq = lane >> 4;
  const int rowA = blockIdx.x * 64 + wv * 16 + m16;
  const int rowC0 = blockIdx.x * 64 + wv * 16 + kq * 4;

  const float* xr = x + (size_t)rowA * 64;
  float xf[8];
  bf16x8 af[2];
  *(float4*)&xf[0] = *(const float4*)(xr + kq * 8);
  *(float4*)&xf[4] = *(const float4*)(xr + kq * 8 + 4);
  af[0] = cvt8(xf);
  *(float4*)&xf[0] = *(const float4*)(xr + 32 + kq * 8);
  *(float4*)&xf[4] = *(const float4*)(xr + 32 + kq * 8 + 4);
  af[1] = cvt8(xf);

  size_t rbase[4];
#pragma unroll
  for (int r = 0; r < 4; r++) {
    const int rc = rowC0 + r;
    const int rr = swap ? (((rc & 255) << 8) | (rc >> 8)) : rc;
    rbase[r] = (size_t)rr * 512;
  }

#pragma unroll 1
  for (int cg = 0; cg < 12; cg++) {
    bf16* dst = (cg < 4) ? q : (cg < 8) ? kk : v;
    const int cbase = (cg & 3) * 128;
#pragma unroll
    for (int ct = 0; ct < 8; ct++) {
      const bf16* wp = Wt + (size_t)(cg * 128 + ct * 16 + m16) * 64 + kq * 8;
      const bf16x8 b0 = *(const bf16x8*)wp;
      const bf16x8 b1 = *(const bf16x8*)(wp + 32);
      f32x4 a = (f32x4){0.f, 0.f, 0.f, 0.f};
      a = MFMA16(af[0], b0, a);
      a = MFMA16(af[1], b1, a);
      const int cloc = cbase + ct * 16 + m16;
#pragma unroll
      for (int r = 0; r < 4; r++)
        dst[rbase[r] + cloc] = __float2bfloat16(a[r]);
    }
  }
}

// ---------------------------------------------------------------- width attention (MFMA) + fused proj
// Inputs are W-MAJOR (row = w*256 + h). grid (WW, NHEADS), block 256 = 4 waves.
// LDS (53248 -> 3 blocks/CU):
//   phase1: Vt[64][256] XOR-swizzled @0 (32768) | Ps[wave][64][40] @32768 (4x5120)
//   phase2: Ot[wave][64][72] @0 (36864) | Wtr[64][72] @36864 (9216)
__global__ void __launch_bounds__(256, 2)
k_width_attn(const bf16* __restrict__ q, const bf16* __restrict__ kk,
             const bf16* __restrict__ v, const float* __restrict__ Wout,
             float* __restrict__ out) {
  __shared__ __align__(16) char smem[53248];
  bf16* Vt = (bf16*)smem;
  const int w = blockIdx.x, head = blockIdx.y;
  const int tid = threadIdx.x, lane = tid & 63, wv = tid >> 6;
  bf16* Ps  = (bf16*)(smem + 32768 + wv * 5120);
  bf16* Ot  = (bf16*)(smem + (size_t)wv * 9216);
  bf16* Wtr = (bf16*)(smem + 36864);
  const int m16 = lane & 15, kq = lane >> 4;

  // stage Vt[d][jOct^(d&7)][j&7] = V[j][d]  (swizzled, stride 256, conflict-free)
  {
    const bf16* src = v + ((size_t)(w * 256 + tid) * 512 + head * 64);
    uint4 rr[8];
#pragma unroll
    for (int c = 0; c < 8; c++) rr[c] = ((const uint4*)src)[c];
    const int jl = tid & 7, jh = tid >> 3;
#pragma unroll
    for (int c = 0; c < 8; c++) {
      const bf16* e = (const bf16*)&rr[c];
#pragma unroll
      for (int t = 0; t < 8; t++) {
        const int d = c * 8 + t;
        Vt[d * 256 + ((jh ^ (d & 7)) << 3) + jl] = e[t];
      }
    }
  }
  // preload Q A-frags (contiguous slab at w*256)
  bf16x8 qf[4][2];
  const int i0 = wv * 64;
#pragma unroll
  for (int it = 0; it < 4; it++) {
    const bf16* b = q + ((size_t)(w * 256 + i0 + it * 16 + m16) * 512 + head * 64 + kq * 8);
    qf[it][0] = *(const bf16x8*)b;
    qf[it][1] = *(const bf16x8*)(b + 32);
  }
  __syncthreads();

  f32x4 acc[4][4];
#pragma unroll
  for (int a = 0; a < 4; a++)
#pragma unroll
    for (int b = 0; b < 4; b++) acc[a][b] = (f32x4){0.f, 0.f, 0.f, 0.f};
  float rsum[4][4];
#pragma unroll
  for (int a = 0; a < 4; a++)
#pragma unroll
    for (int r = 0; r < 4; r++) rsum[a][r] = 0.f;

  auto loadK = [&](int jc, bf16x8 kf[2][2]) {
#pragma unroll
    for (int jt = 0; jt < 2; jt++) {
      const bf16* b = kk + ((size_t)(w * 256 + jc * 32 + jt * 16 + m16) * 512 + head * 64 + kq * 8);
      kf[jt][0] = *(const bf16x8*)b;
      kf[jt][1] = *(const bf16x8*)(b + 32);
    }
  };
  bf16x8 kcur[2][2];
  loadK(0, kcur);

#pragma unroll 1
  for (int jc = 0; jc < 8; jc++) {
    bf16x8 knext[2][2];
    if (jc < 7) loadK(jc + 1, knext);
#pragma unroll
    for (int it = 0; it < 4; it++)
#pragma unroll
      for (int jt = 0; jt < 2; jt++) {
        f32x4 s = (f32x4){0.f, 0.f, 0.f, 0.f};
        s = MFMA16(qf[it][0], kcur[jt][0], s);
        s = MFMA16(qf[it][1], kcur[jt][1], s);
#pragma unroll
        for (int r = 0; r < 4; r++) {
          float p = __expf(s[r] * 0.125f);
          rsum[it][r] += p;
          Ps[(it * 16 + kq * 4 + r) * 40 + jt * 16 + m16] = __float2bfloat16(p);
        }
      }
    bf16x8 pf[4], vf[4];
#pragma unroll
    for (int it = 0; it < 4; it++)
      pf[it] = *(const bf16x8*)&Ps[(it * 16 + m16) * 40 + kq * 8];
#pragma unroll
    for (int dt = 0; dt < 4; dt++)
      vf[dt] = *(const bf16x8*)&Vt[(dt * 16 + m16) * 256 + (((jc * 4 + kq) ^ (m16 & 7)) << 3)];
#pragma unroll
    for (int it = 0; it < 4; it++)
#pragma unroll
      for (int dt = 0; dt < 4; dt++) acc[it][dt] = MFMA16(pf[it], vf[dt], acc[it][dt]);
    if (jc < 7) {
#pragma unroll
      for (int jt = 0; jt < 2; jt++) {
        kcur[jt][0] = knext[jt][0];
        kcur[jt][1] = knext[jt][1];
      }
    }
  }

#pragma unroll
  for (int it = 0; it < 4; it++)
#pragma unroll
    for (int r = 0; r < 4; r++) {
      float s = rsum[it][r];
      s += __shfl_xor(s, 1); s += __shfl_xor(s, 2);
      s += __shfl_xor(s, 4); s += __shfl_xor(s, 8);
      rsum[it][r] = 1.f / s;
    }
  __syncthreads();  // Vt/Ps dead -> Ot/Wtr
#pragma unroll
  for (int it = 0; it < 4; it++)
#pragma unroll
    for (int dt = 0; dt < 4; dt++)
#pragma unroll
      for (int r = 0; r < 4; r++)
        Ot[(it * 16 + kq * 4 + r) * 72 + dt * 16 + m16] =
            __float2bfloat16(acc[it][dt][r] * rsum[it][r]);
  // stage Wtr[c][d] = Wout[head*64+d][c] (epilogue)
#pragma unroll
  for (int s = 0; s < 16; s++) {
    int idx = s * 256 + tid;
    int d = idx >> 6, c = idx & 63;
    Wtr[c * 72 + d] = __float2bfloat16(Wout[(head * 64 + d) * 64 + c]);
  }
  __syncthreads();

  bf16x8 of[4][2], wf[4][2];
#pragma unroll
  for (int it = 0; it < 4; it++) {
    of[it][0] = *(const bf16x8*)&Ot[(it * 16 + m16) * 72 + kq * 8];
    of[it][1] = *(const bf16x8*)&Ot[(it * 16 + m16) * 72 + 32 + kq * 8];
  }
#pragma unroll
  for (int ct = 0; ct < 4; ct++) {
    wf[ct][0] = *(const bf16x8*)&Wtr[(ct * 16 + m16) * 72 + kq * 8];
    wf[ct][1] = *(const bf16x8*)&Wtr[(ct * 16 + m16) * 72 + 32 + kq * 8];
  }
#pragma unroll
  for (int it = 0; it < 4; it++)
#pragma unroll
    for (int ct = 0; ct < 4; ct++) {
      f32x4 c2 = (f32x4){0.f, 0.f, 0.f, 0.f};
      c2 = MFMA16(of[it][0], wf[ct][0], c2);
      c2 = MFMA16(of[it][1], wf[ct][1], c2);
#pragma unroll
      for (int r = 0; r < 4; r++) {
        int i = i0 + it * 16 + kq * 4 + r;
        atomicAdd(&out[(size_t)(i * 256 + w) * 64 + ct * 16 + m16], 0.5f * c2[r]);
      }
    }
}

// ---------------------------------------------------------------- height tied dots (MFMA)
__global__ void __launch_bounds__(256, 2)
k_dots(const bf16* __restrict__ q, const bf16* __restrict__ kk, float* __restrict__ dots) {
  __shared__ __align__(16) char smem[36864];
  bf16* Qs = (bf16*)smem;
  bf16* Ks = (bf16*)(smem + 18432);
  const int tile = blockIdx.x, head = blockIdx.y, rc = blockIdx.z;
  const int i0 = (tile >> 1) * 128, j0 = (tile & 1) * 128;
  const int tid = threadIdx.x, lane = tid & 63, wv = tid >> 6;
  const int m16 = lane & 15, kq = lane >> 4;
  const int ioff = wv * 32;

  f32x4 acc[2][8];
#pragma unroll
  for (int a = 0; a < 2; a++)
#pragma unroll
    for (int b = 0; b < 8; b++) acc[a][b] = (f32x4){0.f, 0.f, 0.f, 0.f};

#pragma unroll 1
  for (int rr = 0; rr < 16; rr++) {
    const int rrow = rc * 16 + rr;
    __syncthreads();
#pragma unroll
    for (int s = 0; s < 4; s++) {
      int idx = s * 256 + tid;
      int row = idx >> 3, ch = idx & 7;
      *(uint4*)&Qs[row * 72 + ch * 8] =
          *(const uint4*)(q + ((size_t)(rrow * 256 + i0 + row) * 512 + head * 64 + ch * 8));
      *(uint4*)&Ks[row * 72 + ch * 8] =
          *(const uint4*)(kk + ((size_t)(rrow * 256 + j0 + row) * 512 + head * 64 + ch * 8));
    }
    __syncthreads();
#pragma unroll
    for (int ks = 0; ks < 2; ks++) {
      bf16x8 af[2], bfr[8];
#pragma unroll
      for (int it = 0; it < 2; it++)
        af[it] = *(const bf16x8*)&Qs[(ioff + it * 16 + m16) * 72 + ks * 32 + kq * 8];
#pragma unroll
      for (int jt = 0; jt < 8; jt++)
        bfr[jt] = *(const bf16x8*)&Ks[(jt * 16 + m16) * 72 + ks * 32 + kq * 8];
#pragma unroll
      for (int it = 0; it < 2; it++)
#pragma unroll
        for (int jt = 0; jt < 8; jt++) acc[it][jt] = MFMA16(af[it], bfr[jt], acc[it][jt]);
    }
  }

  const float sc = 1.f / 128.f;
#pragma unroll
  for (int it = 0; it < 2; it++)
#pragma unroll
    for (int jt = 0; jt < 8; jt++)
#pragma unroll
      for (int r = 0; r < 4; r++) {
        int i = i0 + ioff + it * 16 + kq * 4 + r;
        int j = j0 + jt * 16 + m16;
        atomicAdd(&dots[(size_t)head * 65536 + i * 256 + j], acc[it][jt][r] * sc);
      }
}

// ---------------------------------------------------------------- pair bias: LN + @W_pair
__global__ void __launch_bounds__(256) k_pb(const float* __restrict__ pb,
                                            const float* __restrict__ g,
                                            const float* __restrict__ bb,
                                            const float* __restrict__ Wp,
                                            float* __restrict__ dots) {
  __shared__ float sn[4][128];
  const int tid = threadIdx.x, lane = tid & 63, wv = tid >> 6;
  const size_t ij = (size_t)blockIdx.x * 4 + wv;
  const float2 xv = *(const float2*)(pb + ij * 128 + lane * 2);

  float s = xv.x + xv.y;
#pragma unroll
  for (int o = 1; o < 64; o <<= 1) s += __shfl_xor(s, o);
  const float mu = s * (1.f / 128.f);
  const float d0 = xv.x - mu, d1 = xv.y - mu;
  float s2 = d0 * d0 + d1 * d1;
#pragma unroll
  for (int o = 1; o < 64; o <<= 1) s2 += __shfl_xor(s2, o);
  const float inv = rsqrtf(s2 * (1.f / 128.f) + 1e-5f);

  sn[wv][lane * 2 + 0] = d0 * inv * g[lane * 2 + 0] + bb[lane * 2 + 0];
  sn[wv][lane * 2 + 1] = d1 * inv * g[lane * 2 + 1] + bb[lane * 2 + 1];

  const int h = lane & 7, gp = lane >> 3;
  float a = 0.f;
#pragma unroll
  for (int p0 = 0; p0 < 16; p0++) {
    const int p = gp * 16 + p0;
    a += sn[wv][p] * Wp[p * 8 + h];
  }
  a += __shfl_xor(a, 8);
  a += __shfl_xor(a, 16);
  a += __shfl_xor(a, 32);
  if (lane < 8) dots[(size_t)h * 65536 + ij] += a;
}

// ---------------------------------------------------------------- softmax -> normalized bf16 P
__global__ void __launch_bounds__(256) k_softmax(const float* __restrict__ dots,
                                                 bf16* __restrict__ P) {
  __shared__ float red[4];
  const int i = blockIdx.x, head = blockIdx.y, t = threadIdx.x;
  const size_t base = (size_t)head * 65536 + i * 256;
  const float e = __expf(dots[base + t]);
  float s = e;
#pragma unroll
  for (int o = 1; o < 64; o <<= 1) s += __shfl_xor(s, o);
  if ((t & 63) == 0) red[t >> 6] = s;
  __syncthreads();
  const float S = red[0] + red[1] + red[2] + red[3];
  P[base + t] = __float2bfloat16(e / S);
}

// ---------------------------------------------------------------- height PV (MFMA) + fused proj
// LDS (46080): phase1 Vt[64][256] swizzled @0; phase2 Ot[wave][64][72] @0 | Wtr @36864.
__global__ void __launch_bounds__(256, 2)
k_h_pv(const bf16* __restrict__ P, const bf16* __restrict__ v,
       const float* __restrict__ Wout, float* __restrict__ out) {
  __shared__ __align__(16) char smem[46080];
  bf16* Vt  = (bf16*)smem;
  bf16* Wtr = (bf16*)(smem + 36864);
  const int r = blockIdx.x, head = blockIdx.y;
  const int tid = threadIdx.x, lane = tid & 63, wv = tid >> 6;
  bf16* Ot = (bf16*)(smem + (size_t)wv * 9216);
  const int m16 = lane & 15, kq = lane >> 4;

  {
    const bf16* src = v + ((size_t)(r * 256 + tid) * 512 + head * 64);
    uint4 rr[8];
#pragma unroll
    for (int c = 0; c < 8; c++) rr[c] = ((const uint4*)src)[c];
    const int jl = tid & 7, jh = tid >> 3;
#pragma unroll
    for (int c = 0; c < 8; c++) {
      const bf16* e = (const bf16*)&rr[c];
#pragma unroll
      for (int t = 0; t < 8; t++) {
        const int d = c * 8 + t;
        Vt[d * 256 + ((jh ^ (d & 7)) << 3) + jl] = e[t];
      }
    }
  }

  const bf16* Pb = P + (size_t)head * 65536;
  const int i0 = wv * 64;
  auto loadP = [&](int ks, bf16x8 pf[4]) {
#pragma unroll
    for (int it = 0; it < 4; it++)
      pf[it] = *(const bf16x8*)(Pb + (size_t)(i0 + it * 16 + m16) * 256 + ks * 32 + kq * 8);
  };
  bf16x8 pcur[4];
  loadP(0, pcur);
  __syncthreads();

  f32x4 acc[4][4];
#pragma unroll
  for (int a = 0; a < 4; a++)
#pragma unroll
    for (int b = 0; b < 4; b++) acc[a][b] = (f32x4){0.f, 0.f, 0.f, 0.f};

#pragma unroll 1
  for (int ks = 0; ks < 8; ks++) {
    bf16x8 pnext[4];
    if (ks < 7) loadP(ks + 1, pnext);
    bf16x8 vf[4];
#pragma unroll
    for (int dt = 0; dt < 4; dt++)
      vf[dt] = *(const bf16x8*)&Vt[(dt * 16 + m16) * 256 + (((ks * 4 + kq) ^ (m16 & 7)) << 3)];
#pragma unroll
    for (int it = 0; it < 4; it++)
#pragma unroll
      for (int dt = 0; dt < 4; dt++) acc[it][dt] = MFMA16(pcur[it], vf[dt], acc[it][dt]);
    if (ks < 7) {
#pragma unroll
      for (int it = 0; it < 4; it++) pcur[it] = pnext[it];
    }
  }
  __syncthreads();  // Vt dead -> Ot/Wtr
#pragma unroll
  for (int it = 0; it < 4; it++)
#pragma unroll
    for (int dt = 0; dt < 4; dt++)
#pragma unroll
      for (int r2 = 0; r2 < 4; r2++)
        Ot[(it * 16 + kq * 4 + r2) * 72 + dt * 16 + m16] = __float2bfloat16(acc[it][dt][r2]);
#pragma unroll
  for (int s = 0; s < 16; s++) {
    int idx = s * 256 + tid;
    int d = idx >> 6, c = idx & 63;
    Wtr[c * 72 + d] = __float2bfloat16(Wout[(head * 64 + d) * 64 + c]);
  }
  __syncthreads();

  bf16x8 of[4][2], wf[4][2];
#pragma unroll
  for (int it = 0; it < 4; it++) {
    of[it][0] = *(const bf16x8*)&Ot[(it * 16 + m16) * 72 + kq * 8];
    of[it][1] = *(const bf16x8*)&Ot[(it * 16 + m16) * 72 + 32 + kq * 8];
  }
#pragma unroll
  for (int ct = 0; ct < 4; ct++) {
    wf[ct][0] = *(const bf16x8*)&Wtr[(ct * 16 + m16) * 72 + kq * 8];
    wf[ct][1] = *(const bf16x8*)&Wtr[(ct * 16 + m16) * 72 + 32 + kq * 8];
  }
#pragma unroll
  for (int it = 0; it < 4; it++)
#pragma unroll
    for (int ct = 0; ct < 4; ct++) {
      f32x4 c2 = (f32x4){0.f, 0.f, 0.f, 0.f};
      c2 = MFMA16(of[it][0], wf[ct][0], c2);
      c2 = MFMA16(of[it][1], wf[ct][1], c2);
#pragma unroll
      for (int r2 = 0; r2 < 4; r2++) {
        int i = i0 + it * 16 + kq * 4 + r2;
        atomicAdd(&out[(size_t)(r * 256 + i) * 64 + ct * 16 + m16], 0.5f * c2[r2]);
      }
    }
}

// ================================================================ launch
extern "C" void kernel_launch(void* const* d_in, const int* in_sizes, int n_in,
                              void* d_out, int out_size, void* d_ws, size_t ws_size,
                              hipStream_t stream) {
  const float* x      = (const float*)d_in[0];
  const float* pair   = (const float*)d_in[1];
  const float* Wq_w   = (const float*)d_in[2];
  const float* Wkv_w  = (const float*)d_in[3];
  const float* Wout_w = (const float*)d_in[4];
  const float* bout_w = (const float*)d_in[5];
  const float* Wq_h   = (const float*)d_in[6];
  const float* Wkv_h  = (const float*)d_in[7];
  const float* Wout_h = (const float*)d_in[8];
  const float* bout_h = (const float*)d_in[9];
  const float* ln_g   = (const float*)d_in[10];
  const float* ln_b   = (const float*)d_in[11];
  const float* W_pair = (const float*)d_in[12];
  float* out = (float*)d_out;

  const size_t NE = (size_t)NROWS * 512;
  bf16* q = (bf16*)d_ws;
  bf16* k = q + NE;
  bf16* v = k + NE;
  float* dots = (float*)(v + NE);
  bf16* P = q;
  bf16* Wt_w = (bf16*)dots;
  bf16* Wt_h = Wt_w + 98304;

  k_wt<<<768, 256, 0, stream>>>(Wq_w, Wkv_w, Wq_h, Wkv_h, Wt_w, Wt_h);
  k_init_out<<<NROWS * 64 / 256, 256, 0, stream>>>(bout_w, bout_h, out);

  // -------- width attention (w-major q/k/v) --------
  k_qkv_mfma<<<1024, 256, 0, stream>>>(x, Wt_w, q, k, v, 1);
  k_width_attn<<<dim3(WW, NHEADS), 256, 0, stream>>>(q, k, v, Wout_w, out);

  // -------- height attention (h-major q/k/v) --------
  k_qkv_mfma<<<1024, 256, 0, stream>>>(x, Wt_h, q, k, v, 0);
  hipMemsetAsync(dots, 0, (size_t)8 * 65536 * sizeof(float), stream);
  k_dots<<<dim3(4, NHEADS, 16), 256, 0, stream>>>(q, k, dots);
  k_pb<<<65536 / 4, 256, 0, stream>>>(pair, ln_g, ln_b, W_pair, dots);
  k_softmax<<<dim3(256, NHEADS), 256, 0, stream>>>(dots, P);
  k_h_pv<<<dim3(HH, NHEADS), 256, 0, stream>>>(P, v, Wout_h, out);
}